// Round 8
// baseline (128.909 us; speedup 1.0000x reference)
//
#include <hip/hip_runtime.h>
#include <hip/hip_bf16.h>

#define NVOX 100000
#define CIN 32
#define COUT 32
#define KOFF 27
#define NTILE 6250            // NVOX / 16 exactly

typedef __attribute__((ext_vector_type(8))) short short8;
typedef __attribute__((ext_vector_type(4))) float float4v;

// fp32 -> bf16 round-to-nearest-even (finite inputs)
__device__ __forceinline__ short f2bf(float x) {
    union { float f; unsigned u; } v; v.f = x;
    unsigned u = v.u;
    u += 0x7FFFu + ((u >> 16) & 1u);
    return (short)(u >> 16);
}

// ---- pre-pass A: features fp32 -> bf16 (+ zero row at index NVOX) ----
__global__ __launch_bounds__(256) void feat_cvt_kernel(
    const float* __restrict__ feat, unsigned short* __restrict__ fbf)
{
    int i = (blockIdx.x * 256 + threadIdx.x) * 4;
    if (i < NVOX * CIN) {
        float4v f = *(const float4v*)(feat + i);
        short s[4] = { f2bf(f.x), f2bf(f.y), f2bf(f.z), f2bf(f.w) };
        *(ulonglong1*)(fbf + i) = *(ulonglong1*)s;
    } else if (i < (NVOX + 1) * CIN) {
        short s[4] = { 0, 0, 0, 0 };               // zero row for masked gathers
        *(ulonglong1*)(fbf + i) = *(ulonglong1*)s;
    }
}

// ---- pre-pass B: weights fp32 -> bf16 in B-fragment order ----
// wfrag[k*128 + t*64 + ln][j] = W[k][ci=(ln>>4)*8+j][co=t*16+(ln&15)]
__global__ __launch_bounds__(256) void wgt_cvt_kernel(
    const float* __restrict__ weight, short8* __restrict__ wfrag)
{
    int g = blockIdx.x * 256 + threadIdx.x;
    if (g >= KOFF * 2 * 64) return;
    int k   = g >> 7;
    int rem = g & 127;
    int t   = rem >> 6;
    int ln  = rem & 63;
    int co  = t * 16 + (ln & 15);
    int cib = (ln >> 4) * 8;
    const float* wp = weight + (k * CIN + cib) * COUT + co;
    short8 b;
#pragma unroll
    for (int j = 0; j < 8; ++j) b[j] = f2bf(wp[j * COUT]);
    wfrag[g] = b;
}

// ---- pre-pass C: per-16-voxel-tile offset compaction ----
// For tile t: cnt_g[t] = #offsets with any live neighbor;
// koff[t*32+j] = k*128 (wlds index); cenc[(t*27+j)*16+m] = gather byte offset.
__global__ __launch_bounds__(256) void compact_kernel(
    const int* __restrict__ nbr_idx, const int* __restrict__ nbr_mask,
    int* __restrict__ cenc, int* __restrict__ koff, int* __restrict__ cnt_g)
{
    __shared__ int elds[4][KOFF * 17];             // [wave][k*17+m], +1 pad
    const int tid  = threadIdx.x;
    const int lane = tid & 63;
    const int wave = tid >> 6;
    const int tile = blockIdx.x * 4 + wave;        // one tile per wave, no barriers
    if (tile >= NTILE) return;

    const int base = tile * 16 * KOFF;
#pragma unroll
    for (int i = 0; i < 7; ++i) {
        int p = lane + i * 64;                     // (v,k) pair within tile
        if (p < 16 * KOFF) {
            int id = nbr_idx[base + p];
            int mk = nbr_mask[base + p];
            int v  = p / KOFF;
            int k  = p - v * KOFF;
            elds[wave][k * 17 + v] = (mk ? id : NVOX) << 6;
        }
    }
    // wave-private LDS region: compiler's lgkmcnt waits order write->read
    int live = 0;
    if (lane < KOFF) {
#pragma unroll
        for (int mm = 0; mm < 16; ++mm)
            live |= (elds[wave][lane * 17 + mm] != (NVOX << 6));
    }
    unsigned long long bal = __ballot(live != 0);  // wave-uniform
    int cnt = __popcll(bal);
    int j = 0;
    while (bal) {
        int k = (int)__builtin_ctzll(bal);
        bal &= bal - 1;
        int e = elds[wave][k * 17 + (lane & 15)];
        if (lane < 16) cenc[(tile * KOFF + j) * 16 + lane] = e;
        if (lane == 0) koff[tile * 32 + j] = k * 128;
        ++j;
    }
    if (cnt == 0) {                                // defensive; center is always live
        if (lane < 16) cenc[tile * KOFF * 16 + lane] = NVOX << 6;
        if (lane == 0) koff[tile * 32] = 0;
        cnt = 1;
    }
    if (lane == 0) cnt_g[tile] = cnt;
}

__global__ __launch_bounds__(512, 4) void subm_conv_kernel(
    const unsigned short* __restrict__ fbf,   // bf16 features [N+1,32] (ws)
    const short8* __restrict__ wfrag,         // bf16 B-fragments (ws)
    const float* __restrict__ bias,           // fp32 [32]
    const int* __restrict__ cenc,             // compact gather offsets (ws)
    const int* __restrict__ koff,             // compact wlds indices (ws)
    const int* __restrict__ cnt_g,            // per-tile live-offset count (ws)
    float* __restrict__ out)                  // fp32 [N,32]
{
    __shared__ short8 wlds[KOFF * 2 * 64];

    const int tid = threadIdx.x;
    for (int g = tid; g < KOFF * 2 * 64; g += 512) wlds[g] = wfrag[g];

    const int lane = tid & 63;
    const int wave = tid >> 6;
    const int m    = lane & 15;
    const int quad = lane >> 4;
    const int tile = blockIdx.x * 8 + wave;

    __syncthreads();
    if (tile >= NTILE) return;

    const int cnt = cnt_g[tile];                   // broadcast (1 line)
    const int jm  = cnt - 1;
    const int* cb = cenc + tile * KOFF * 16;
    const int* kb = koff + tile * 32;
    const char* fb = (const char*)fbf;
    const int boff = quad * 16;

    // software pipeline: invariant at iter j: a0=A(j), a1=A(j+1),
    // ce2=ce(j+2), ko0=ko(j), ko1=ko(j+1). Clamped indices, no pads needed.
    int j1 = 1 > jm ? jm : 1;
    int j2 = 2 > jm ? jm : 2;
    int ce0 = cb[m];
    int ce1 = cb[j1 * 16 + m];
    int ce2 = cb[j2 * 16 + m];
    int ko0 = kb[0];
    int ko1 = kb[j1];
    short8 a0 = *(const short8*)(fb + (size_t)(unsigned)ce0 + boff);
    short8 a1 = *(const short8*)(fb + (size_t)(unsigned)ce1 + boff);

    float4v acc0 = {0.f, 0.f, 0.f, 0.f};
    float4v acc1 = {0.f, 0.f, 0.f, 0.f};

    for (int j = 0; j < cnt; ++j) {
        short8 a = a0;
        int   ko = ko0;
        a0  = a1;
        ko0 = ko1;
        int ce_n = ce2;                            // ce(j+2)
        int jn = j + 3; jn = jn > jm ? jm : jn;
        ce2 = cb[jn * 16 + m];
        int kn = j + 2; kn = kn > jm ? jm : kn;
        ko1 = kb[kn];
        a1 = *(const short8*)(fb + (size_t)(unsigned)ce_n + boff);

        short8 wb0 = wlds[ko + lane];
        short8 wb1 = wlds[ko + 64 + lane];
        acc0 = __builtin_amdgcn_mfma_f32_16x16x32_bf16(a, wb0, acc0, 0, 0, 0);
        acc1 = __builtin_amdgcn_mfma_f32_16x16x32_bf16(a, wb1, acc1, 0, 0, 0);
    }

    // C/D layout: col (cout) = lane&15, row (voxel within tile) = quad*4 + reg
    const float bs0 = bias[m];
    const float bs1 = bias[16 + m];
    const int v0 = tile * 16;
#pragma unroll
    for (int r = 0; r < 4; ++r) {
        int vv = v0 + quad * 4 + r;                // always < NVOX (6250*16 = N)
        out[(size_t)vv * COUT + m]      = acc0[r] + bs0;
        out[(size_t)vv * COUT + 16 + m] = acc1[r] + bs1;
    }
}

extern "C" void kernel_launch(void* const* d_in, const int* in_sizes, int n_in,
                              void* d_out, int out_size, void* d_ws, size_t ws_size,
                              hipStream_t stream) {
    const float* feat = (const float*)d_in[0];
    const float* wgt  = (const float*)d_in[1];
    const float* bias = (const float*)d_in[2];
    const int*   nidx = (const int*)d_in[3];
    const int*   nmsk = (const int*)d_in[4];
    float*       out  = (float*)d_out;

    char* ws = (char*)d_ws;
    unsigned short* fbf   = (unsigned short*)ws;                 // 6,400,064 B
    short8*         wfrag = (short8*)(ws + 6400128);             //    55,296 B
    int*            cenc  = (int*)(ws + 6455424);                // 10,800,000 B
    int*            koff  = (int*)(ws + 17255424);               //   800,000 B
    int*            cntg  = (int*)(ws + 18055424);               //    25,000 B

    feat_cvt_kernel<<<((NVOX + 1) * CIN / 4 + 255) / 256, 256, 0, stream>>>(feat, fbf);
    wgt_cvt_kernel<<<(KOFF * 2 * 64 + 255) / 256, 256, 0, stream>>>(wgt, wfrag);
    compact_kernel<<<(NTILE + 3) / 4, 256, 0, stream>>>(nidx, nmsk, cenc, koff, cntg);

    const int block = 512;                         // 8 waves = 8 tiles = 128 voxels
    const int grid  = (NTILE + 7) / 8;             // 782
    subm_conv_kernel<<<grid, block, 0, stream>>>(fbf, wfrag, bias, cenc, koff, cntg, out);
}

// Round 9
// 109.578 us; speedup vs baseline: 1.1764x; 1.1764x over previous
//
#include <hip/hip_runtime.h>
#include <hip/hip_bf16.h>

#define NVOX 100000
#define CIN 32
#define COUT 32
#define KOFF 27
#define NTILE 6250            // NVOX / 16 exactly

typedef __attribute__((ext_vector_type(8))) short short8;
typedef __attribute__((ext_vector_type(4))) float float4v;
typedef __attribute__((ext_vector_type(4))) int   int4v;

// fp32 -> bf16 round-to-nearest-even (finite inputs)
__device__ __forceinline__ short f2bf(float x) {
    union { float f; unsigned u; } v; v.f = x;
    unsigned u = v.u;
    u += 0x7FFFu + ((u >> 16) & 1u);
    return (short)(u >> 16);
}

// ---- pre-pass A: features fp32 -> bf16 (+ zero row at index NVOX) ----
__global__ __launch_bounds__(256) void feat_cvt_kernel(
    const float* __restrict__ feat, unsigned short* __restrict__ fbf)
{
    int i = (blockIdx.x * 256 + threadIdx.x) * 4;
    if (i < NVOX * CIN) {
        float4v f = *(const float4v*)(feat + i);
        short s[4] = { f2bf(f.x), f2bf(f.y), f2bf(f.z), f2bf(f.w) };
        *(ulonglong1*)(fbf + i) = *(ulonglong1*)s;
    } else if (i < (NVOX + 1) * CIN) {
        short s[4] = { 0, 0, 0, 0 };               // zero row for masked gathers
        *(ulonglong1*)(fbf + i) = *(ulonglong1*)s;
    }
}

// ---- pre-pass B: weights fp32 -> bf16 in B-fragment order ----
// wfrag[k*128 + t*64 + ln][j] = W[k][ci=(ln>>4)*8+j][co=t*16+(ln&15)]
__global__ __launch_bounds__(256) void wgt_cvt_kernel(
    const float* __restrict__ weight, short8* __restrict__ wfrag)
{
    int g = blockIdx.x * 256 + threadIdx.x;
    if (g >= KOFF * 2 * 64) return;
    int k   = g >> 7;
    int rem = g & 127;
    int t   = rem >> 6;
    int ln  = rem & 63;
    int co  = t * 16 + (ln & 15);
    int cib = (ln >> 4) * 8;
    const float* wp = weight + (k * CIN + cib) * COUT + co;
    short8 b;
#pragma unroll
    for (int j = 0; j < 8; ++j) b[j] = f2bf(wp[j * COUT]);
    wfrag[g] = b;
}

__global__ __launch_bounds__(256, 4) void subm_conv_kernel(
    const unsigned short* __restrict__ fbf,   // bf16 features [N+1,32] (ws)
    const short8* __restrict__ wfrag,         // bf16 B-fragments (ws)
    const float* __restrict__ bias,           // fp32 [32]
    const int* __restrict__ nbr_idx,          // int32 [N,27]
    const int* __restrict__ nbr_mask,         // bool -> int32 [N,27]
    float* __restrict__ out)                  // fp32 [N,32]
{
    __shared__ short8 wlds[KOFF * 2 * 64];    // 55,296 B
    __shared__ int    elds[4 * 16 * KOFF];    //  6,912 B (per-wave strips)

    const int tid  = threadIdx.x;
    const int lane = tid & 63;
    const int wave = tid >> 6;                 // 0..3
    const int m    = lane & 15;
    const int quad = lane >> 4;
    const int tile = blockIdx.x * 4 + wave;    // 16 voxels per tile
    const bool tv  = tile < NTILE;

    // ---- coalesced metadata: 108 int4 per tile (idx + mask), 2+2 loads/wave ----
    const int base4 = tile * (16 * KOFF / 4);  // int4 index
    int4v id0, id1, mk0, mk1;
    const int p4a = lane, p4b = lane + 64;     // int4 positions within tile
    if (tv) {
        id0 = ((const int4v*)nbr_idx)[base4 + p4a];
        mk0 = ((const int4v*)nbr_mask)[base4 + p4a];
        if (p4b < 108) {
            id1 = ((const int4v*)nbr_idx)[base4 + p4b];
            mk1 = ((const int4v*)nbr_mask)[base4 + p4b];
        }
    }

    // stage weights while metadata loads are in flight
    for (int g = tid; g < KOFF * 2 * 64; g += 256) wlds[g] = wfrag[g];

    // fold mask into byte offsets, park in wave-private LDS strip (layout p = v*27+k)
    int* ew = elds + wave * (16 * KOFF);
    if (tv) {
        int4v e0, e1;
        e0.x = mk0.x ? (id0.x << 6) : (NVOX << 6);
        e0.y = mk0.y ? (id0.y << 6) : (NVOX << 6);
        e0.z = mk0.z ? (id0.z << 6) : (NVOX << 6);
        e0.w = mk0.w ? (id0.w << 6) : (NVOX << 6);
        ((int4v*)ew)[p4a] = e0;
        if (p4b < 108) {
            e1.x = mk1.x ? (id1.x << 6) : (NVOX << 6);
            e1.y = mk1.y ? (id1.y << 6) : (NVOX << 6);
            e1.z = mk1.z ? (id1.z << 6) : (NVOX << 6);
            e1.w = mk1.w ? (id1.w << 6) : (NVOX << 6);
            ((int4v*)ew)[p4b] = e1;
        }
    }
    __syncthreads();
    if (!tv) return;

    const char* fb   = (const char*)fbf;
    const int   boff = quad * 16;              // byte offset of A-frag in row
    const int*  em   = ew + m * KOFF;          // this lane's voxel metadata row

    float4v acc0 = {0.f, 0.f, 0.f, 0.f};
    float4v acc1 = {0.f, 0.f, 0.f, 0.f};

    // ---- depth-8 rotating gather pipeline, fully unrolled (R5-proven) ----
    short8 abuf[8];
#pragma unroll
    for (int k = 0; k < 8; ++k)
        abuf[k] = *(const short8*)(fb + (size_t)(unsigned)em[k] + boff);

#pragma unroll
    for (int k = 0; k < KOFF; ++k) {
        const int slot = k & 7;
        short8 a = abuf[slot];
        if (k + 8 < KOFF)
            abuf[slot] = *(const short8*)(fb + (size_t)(unsigned)em[k + 8] + boff);

        short8 wb0 = wlds[k * 128 + lane];
        short8 wb1 = wlds[k * 128 + 64 + lane];
        acc0 = __builtin_amdgcn_mfma_f32_16x16x32_bf16(a, wb0, acc0, 0, 0, 0);
        acc1 = __builtin_amdgcn_mfma_f32_16x16x32_bf16(a, wb1, acc1, 0, 0, 0);
    }

    // C/D layout: col (cout) = lane&15, row (voxel within tile) = quad*4 + reg
    const float bs0 = bias[m];
    const float bs1 = bias[16 + m];
    const int v0 = tile * 16;
#pragma unroll
    for (int r = 0; r < 4; ++r) {
        int vv = v0 + quad * 4 + r;                // always < NVOX (NTILE*16 == NVOX)
        out[(size_t)vv * COUT + m]      = acc0[r] + bs0;
        out[(size_t)vv * COUT + 16 + m] = acc1[r] + bs1;
    }
}

extern "C" void kernel_launch(void* const* d_in, const int* in_sizes, int n_in,
                              void* d_out, int out_size, void* d_ws, size_t ws_size,
                              hipStream_t stream) {
    const float* feat = (const float*)d_in[0];
    const float* wgt  = (const float*)d_in[1];
    const float* bias = (const float*)d_in[2];
    const int*   nidx = (const int*)d_in[3];
    const int*   nmsk = (const int*)d_in[4];
    float*       out  = (float*)d_out;

    char* ws = (char*)d_ws;
    unsigned short* fbf   = (unsigned short*)ws;                 // 6,400,064 B
    short8*         wfrag = (short8*)(ws + 6400128);             //    55,296 B

    feat_cvt_kernel<<<((NVOX + 1) * CIN / 4 + 255) / 256, 256, 0, stream>>>(feat, fbf);
    wgt_cvt_kernel<<<(KOFF * 2 * 64 + 255) / 256, 256, 0, stream>>>(wgt, wfrag);

    const int block = 256;                         // 4 waves = 4 tiles = 64 voxels
    const int grid  = (NTILE + 3) / 4;             // 1563
    subm_conv_kernel<<<grid, block, 0, stream>>>(fbf, wfrag, bias, nidx, nmsk, out);
}

// Round 10
// 99.191 us; speedup vs baseline: 1.2996x; 1.1047x over previous
//
#include <hip/hip_runtime.h>
#include <hip/hip_bf16.h>

#define NVOX 100000
#define CIN 32
#define COUT 32
#define KOFF 27
#define NTILE 6250            // NVOX / 16 exactly

typedef __attribute__((ext_vector_type(8))) short short8;
typedef __attribute__((ext_vector_type(4))) float float4v;

// fp32 -> bf16 round-to-nearest-even (finite inputs)
__device__ __forceinline__ short f2bf(float x) {
    union { float f; unsigned u; } v; v.f = x;
    unsigned u = v.u;
    u += 0x7FFFu + ((u >> 16) & 1u);
    return (short)(u >> 16);
}

#define FEAT_BLOCKS 3126      // ceil((NVOX+1)*CIN/4 / 256)

// ---- fused pre-pass: features fp32->bf16 (+zero row) AND weight B-fragments ----
__global__ __launch_bounds__(256) void cvt_kernel(
    const float* __restrict__ feat, const float* __restrict__ weight,
    unsigned short* __restrict__ fbf, short8* __restrict__ wfrag)
{
    if (blockIdx.x < FEAT_BLOCKS) {
        int i = (blockIdx.x * 256 + threadIdx.x) * 4;
        if (i < NVOX * CIN) {
            float4v f = *(const float4v*)(feat + i);
            short s[4] = { f2bf(f.x), f2bf(f.y), f2bf(f.z), f2bf(f.w) };
            *(ulonglong1*)(fbf + i) = *(ulonglong1*)s;
        } else if (i < (NVOX + 1) * CIN) {
            short s[4] = { 0, 0, 0, 0 };           // zero row for masked gathers
            *(ulonglong1*)(fbf + i) = *(ulonglong1*)s;
        }
    } else {
        // wfrag[k*128 + t*64 + ln][j] = W[k][ci=(ln>>4)*8+j][co=t*16+(ln&15)]
        int g = (blockIdx.x - FEAT_BLOCKS) * 256 + threadIdx.x;
        if (g >= KOFF * 2 * 64) return;
        int k   = g >> 7;
        int rem = g & 127;
        int t   = rem >> 6;
        int ln  = rem & 63;
        int co  = t * 16 + (ln & 15);
        int cib = (ln >> 4) * 8;
        const float* wp = weight + (k * CIN + cib) * COUT + co;
        short8 b;
#pragma unroll
        for (int j = 0; j < 8; ++j) b[j] = f2bf(wp[j * COUT]);
        wfrag[g] = b;
    }
}

__global__ __launch_bounds__(512, 4) void subm_conv_kernel(
    const unsigned short* __restrict__ fbf,   // bf16 features [N+1,32] (ws)
    const short8* __restrict__ wfrag,         // bf16 B-fragments (ws)
    const float* __restrict__ bias,           // fp32 [32]
    const int* __restrict__ nbr_idx,          // int32 [N,27]
    const int* __restrict__ nbr_mask,         // bool -> int32 [N,27]
    float* __restrict__ out)                  // fp32 [N,32]
{
    __shared__ short8 wlds[KOFF * 2 * 64];    // 55,296 B; reused as store buffer

    const int tid  = threadIdx.x;
    const int lane = tid & 63;
    const int wave = tid >> 6;                 // 0..7
    const int m    = lane & 15;
    const int quad = lane >> 4;
    const int tile = blockIdx.x * 8 + wave;    // 16 voxels per wave
    const bool tv  = tile < NTILE;

    const int v0 = tile * 16;
    int v = v0 + m;
    if (v > NVOX - 1) v = NVOX - 1;            // clamp loads (invalid waves idle)
    const int base = v * KOFF;

    // metadata: all 27 idx + 27 masks issued up front (R5-proven)
    int enc[KOFF];
#pragma unroll
    for (int k = 0; k < KOFF; ++k) enc[k] = nbr_idx[base + k];
    int mok[KOFF];
#pragma unroll
    for (int k = 0; k < KOFF; ++k) mok[k] = nbr_mask[base + k];
#pragma unroll
    for (int k = 0; k < KOFF; ++k) enc[k] = (mok[k] ? enc[k] : NVOX) << 6;

    for (int g = tid; g < KOFF * 2 * 64; g += 512) wlds[g] = wfrag[g];
    __syncthreads();

    float4v acc0 = {0.f, 0.f, 0.f, 0.f};
    float4v acc1 = {0.f, 0.f, 0.f, 0.f};

    const char* fb   = (const char*)fbf;
    const int   boff = quad * 16;              // byte offset of A-frag in row

    // ---- depth-8 rotating gather pipeline, fully unrolled (R5-proven) ----
    short8 abuf[8];
#pragma unroll
    for (int k = 0; k < 8; ++k)
        abuf[k] = *(const short8*)(fb + (size_t)(unsigned)enc[k] + boff);

#pragma unroll
    for (int k = 0; k < KOFF; ++k) {
        const int slot = k & 7;
        short8 a = abuf[slot];
        if (k + 8 < KOFF)
            abuf[slot] = *(const short8*)(fb + (size_t)(unsigned)enc[k + 8] + boff);

        short8 wb0 = wlds[k * 128 + lane];
        short8 wb1 = wlds[k * 128 + 64 + lane];
        acc0 = __builtin_amdgcn_mfma_f32_16x16x32_bf16(a, wb0, acc0, 0, 0, 0);
        acc1 = __builtin_amdgcn_mfma_f32_16x16x32_bf16(a, wb1, acc1, 0, 0, 0);
    }

    // ---- coalesced epilogue: transpose through LDS, store full 128B rows ----
    // All waves did exactly 27 iterations -> barrier is cheap and non-divergent.
    __syncthreads();                           // wlds reads done; safe to reuse
    float* tb = (float*)wlds + wave * (16 * 36);   // 16 rows, stride 36 (pad: 2-way banks)

    const float bs0 = bias[m];
    const float bs1 = bias[16 + m];
    if (tv) {
        // C/D layout: col (cout) = lane&15, row (voxel) = quad*4 + reg
#pragma unroll
        for (int r = 0; r < 4; ++r) {
            tb[(quad * 4 + r) * 36 + m]      = acc0[r] + bs0;
            tb[(quad * 4 + r) * 36 + 16 + m] = acc1[r] + bs1;
        }
#pragma unroll
        for (int p = 0; p < 2; ++p) {
            int flat = p * 64 + lane;          // 0..127
            int row  = flat >> 3;              // 8 lanes per 128B row
            int ch   = flat & 7;               // 16B chunk within row
            float4v val = *(const float4v*)(tb + row * 36 + ch * 4);
            *(float4v*)(out + (size_t)(v0 + row) * COUT + ch * 4) = val;
        }
    }
}

extern "C" void kernel_launch(void* const* d_in, const int* in_sizes, int n_in,
                              void* d_out, int out_size, void* d_ws, size_t ws_size,
                              hipStream_t stream) {
    const float* feat = (const float*)d_in[0];
    const float* wgt  = (const float*)d_in[1];
    const float* bias = (const float*)d_in[2];
    const int*   nidx = (const int*)d_in[3];
    const int*   nmsk = (const int*)d_in[4];
    float*       out  = (float*)d_out;

    char* ws = (char*)d_ws;
    unsigned short* fbf   = (unsigned short*)ws;                 // 6,400,064 B
    short8*         wfrag = (short8*)(ws + 6400128);             //    55,296 B

    const int wgt_blocks = (KOFF * 2 * 64 + 255) / 256;          // 14
    cvt_kernel<<<FEAT_BLOCKS + wgt_blocks, 256, 0, stream>>>(feat, wgt, fbf, wfrag);

    const int block = 512;                         // 8 waves = 8 tiles = 128 voxels
    const int grid  = (NTILE + 7) / 8;             // 782
    subm_conv_kernel<<<grid, block, 0, stream>>>(fbf, wfrag, bias, nidx, nmsk, out);
}